// Round 15
// baseline (100.059 us; speedup 1.0000x reference)
//
#include <hip/hip_runtime.h>

#define T_SEQ 4096
#define DMODEL 1024
#define NHEAD 16
#define HDIM 64
#define WIN 128

typedef __attribute__((ext_vector_type(8))) short bf16x8;
typedef __attribute__((ext_vector_type(4))) float f32x4;
typedef __attribute__((ext_vector_type(4))) unsigned short u16x4;

__device__ __forceinline__ unsigned short f2bf(float f) {
  unsigned int u = __builtin_bit_cast(unsigned int, f);
  return (unsigned short)((u + 0x7fffu + ((u >> 16) & 1u)) >> 16);
}

__device__ __forceinline__ void gload_lds16(const unsigned short* g,
                                            unsigned short* l) {
  __builtin_amdgcn_global_load_lds(
      (const __attribute__((address_space(1))) void*)g,
      (__attribute__((address_space(3))) void*)l, 16, 0, 0);
}

// ---------------- fused fp32 -> bf16 converts (one launch) ----------------
__global__ void convert_all(const float* __restrict__ x,
                            const float* __restrict__ w_in,
                            const float* __restrict__ w_out,
                            unsigned short* __restrict__ x_bf,
                            unsigned short* __restrict__ w_in_bf,
                            unsigned short* __restrict__ w_out_bf) {
  int stride = gridDim.x * blockDim.x;
  int t0 = blockIdx.x * blockDim.x + threadIdx.x;
#define CVT(SRC, DST, N4)                                          \
  for (int i = t0; i < (N4); i += stride) {                        \
    float4 v = reinterpret_cast<const float4*>(SRC)[i];            \
    u16x4 o;                                                       \
    o.x = f2bf(v.x); o.y = f2bf(v.y); o.z = f2bf(v.z); o.w = f2bf(v.w); \
    reinterpret_cast<u16x4*>(DST)[i] = o;                          \
  }
  CVT(x, x_bf, T_SEQ * DMODEL / 4)
  CVT(w_in, w_in_bf, 3 * DMODEL * DMODEL / 4)
  CVT(w_out, w_out_bf, DMODEL * DMODEL / 4)
#undef CVT
}

// ======================= qkv: 8-phase 256x256 GEMM ========================
// 512 thr / 8 waves (2Mx4N), wave-tile 128x64, BK=64, 2 tiles per 8-phase
// iteration, K=1024 -> 8 iters. Reg-staged K-half units (A/B alternate per
// phase), full 3-bit XOR LDS swizzle (0-conflict reads AND writes). Unit
// ledger (verified): every unit written >=6 phases before first read
// (published by s_barrier), >=1 phase after last reader's lgkm drain.
// Loads issue 2 phases ahead of their ds_write (compiler auto-vmcnt).
__global__ __launch_bounds__(512, 2) void qkv_gemm8(
    const unsigned short* __restrict__ A,   // x_bf   [4096][1024]
    const unsigned short* __restrict__ B,   // w_in_bf[3072][1024]
    const float* __restrict__ bias,
    unsigned short* __restrict__ q_buf,
    unsigned short* __restrict__ k_buf,
    unsigned short* __restrict__ vt_buf) {
  const int K = DMODEL;
  __shared__ __align__(16) unsigned short As[2][256 * 64];
  __shared__ __align__(16) unsigned short Bs[2][256 * 64];

  int tid = threadIdx.x;
  int lane = tid & 63, wave = tid >> 6;
  int wr = wave >> 2, wc = wave & 3;       // 2 x 4 wave grid
  int lo = lane & 15, hi = lane >> 4;      // hi in 0..3
  int t0 = blockIdx.y * 256, e0 = blockIdx.x * 256;
  int swrow = wave * 16 + lo;              // stage row 0..127 (+128 for 2nd)
  int spos7 = swrow & 7;

  f32x4 acc[8][4];
#pragma unroll
  for (int m = 0; m < 8; ++m)
#pragma unroll
    for (int n = 0; n < 4; ++n) acc[m][n] = (f32x4){0.f, 0.f, 0.f, 0.f};

  bf16x8 uA0, uA1, uB0, uB1, bfr[4];

  auto ldA = [&](int tt, int kh) {
    const unsigned short* g =
        A + (size_t)(t0 + swrow) * K + tt * 64 + kh * 32 + hi * 8;
    uA0 = *reinterpret_cast<const bf16x8*>(g);
    uA1 = *reinterpret_cast<const bf16x8*>(g + (size_t)128 * K);
  };
  auto ldB = [&](int tt, int kh) {
    const unsigned short* g =
        B + (size_t)(e0 + swrow) * K + tt * 64 + kh * 32 + hi * 8;
    uB0 = *reinterpret_cast<const bf16x8*>(g);
    uB1 = *reinterpret_cast<const bf16x8*>(g + (size_t)128 * K);
  };
  auto wrA = [&](int kh, int buf) {
    int pos = (((kh << 2) | hi) ^ spos7) * 8;
    *reinterpret_cast<bf16x8*>(&As[buf][swrow * 64 + pos]) = uA0;
    *reinterpret_cast<bf16x8*>(&As[buf][(swrow + 128) * 64 + pos]) = uA1;
  };
  auto wrB = [&](int kh, int buf) {
    int pos = (((kh << 2) | hi) ^ spos7) * 8;
    *reinterpret_cast<bf16x8*>(&Bs[buf][swrow * 64 + pos]) = uB0;
    *reinterpret_cast<bf16x8*>(&Bs[buf][(swrow + 128) * 64 + pos]) = uB1;
  };

  // ---- prologue: tiles 0,1 fully staged except A(1).k1 (arrives at p1) ---
  ldA(0, 0); wrA(0, 0);
  ldA(0, 1); wrA(1, 0);
  ldA(1, 0); wrA(0, 1);
  ldB(0, 0); wrB(0, 0);
  ldB(0, 1); wrB(1, 0);
  ldB(1, 0); wrB(0, 1);
  ldB(1, 1); wrB(1, 1);
  ldA(1, 1);   // p1's write unit
  ldB(2, 0);   // p2's write unit
  __syncthreads();

#define LGKM0() asm volatile("s_waitcnt lgkmcnt(0)" ::: "memory")
#define BARR() asm volatile("s_barrier" ::: "memory")
#define PHASE(MH, KS, BUF, WRSTMT, LDSTMT)                                  \
  {                                                                         \
    bf16x8 af[4];                                                           \
    _Pragma("unroll") for (int fm = 0; fm < 4; ++fm) {                      \
      int grow = wr * 128 + MH * 64 + fm * 16 + lo;                         \
      af[fm] = *reinterpret_cast<const bf16x8*>(                            \
          &As[BUF][grow * 64 + ((((KS) << 2) | hi) ^ (grow & 7)) * 8]);     \
    }                                                                       \
    if ((MH) == 0) {                                                        \
      _Pragma("unroll") for (int fn = 0; fn < 4; ++fn) {                    \
        int brow = wc * 64 + fn * 16 + lo;                                  \
        bfr[fn] = *reinterpret_cast<const bf16x8*>(                         \
            &Bs[BUF][brow * 64 + ((((KS) << 2) | hi) ^ (brow & 7)) * 8]);   \
      }                                                                     \
    }                                                                       \
    WRSTMT;                                                                 \
    LDSTMT;                                                                 \
    LGKM0();                                                                \
    BARR();                                                                 \
    __builtin_amdgcn_s_setprio(1);                                          \
    _Pragma("unroll") for (int fm = 0; fm < 4; ++fm)                        \
        _Pragma("unroll") for (int fn = 0; fn < 4; ++fn)                    \
            acc[(MH) * 4 + fm][fn] = __builtin_amdgcn_mfma_f32_16x16x32_bf16( \
                af[fm], bfr[fn], acc[(MH) * 4 + fm][fn], 0, 0, 0);          \
    __builtin_amdgcn_s_setprio(0);                                          \
    BARR();                                                                 \
  }

#pragma unroll 1
  for (int i = 0; i < 8; ++i) {
    int T2 = 2 * i + 2, T3 = 2 * i + 3, T4 = 2 * i + 4;
    bool g7 = (i < 7), g6 = (i < 6);
    // tiles: T0=2i in buf0 (p1-4), T1=2i+1 in buf1 (p5-8)
    PHASE(0, 0, 0, { wrA(1, 1); },            { if (g7) ldA(T2, 0); })  // p1
    PHASE(1, 0, 0, { if (g7) wrB(0, 0); },    { if (g7) ldB(T2, 1); })  // p2
    PHASE(0, 1, 0, { if (g7) wrA(0, 0); },    { if (g7) ldA(T2, 1); })  // p3
    PHASE(1, 1, 0, { if (g7) wrB(1, 0); },    { if (g7) ldB(T3, 0); })  // p4
    PHASE(0, 0, 1, { if (g7) wrA(1, 0); },    { if (g7) ldA(T3, 0); })  // p5
    PHASE(1, 0, 1, { if (g7) wrB(0, 1); },    { if (g7) ldB(T3, 1); })  // p6
    PHASE(0, 1, 1, { if (g7) wrA(0, 1); },    { if (g7) ldA(T3, 1); })  // p7
    PHASE(1, 1, 1, { if (g7) wrB(1, 1); },    { if (g6) ldB(T4, 0); })  // p8
    (void)T2; (void)T3; (void)T4;
  }
#undef PHASE
#undef BARR
#undef LGKM0

  // ---- epilogue: +bias, scatter q/k/vt (vt packed x4) ----
  int t0w = t0 + wr * 128;
  int e0w = e0 + wc * 64;
#pragma unroll
  for (int m = 0; m < 8; ++m) {
#pragma unroll
    for (int n = 0; n < 4; ++n) {
      int e = e0w + n * 16 + lo;
      float bv = bias[e];
      int part = e >> 10;
      int h = (e >> 6) & 15;
      int d = e & 63;
      if (part == 2) {
        int t = t0w + m * 16 + hi * 4;
        u16x4 pk;
        pk.x = f2bf(acc[m][n][0] + bv);
        pk.y = f2bf(acc[m][n][1] + bv);
        pk.z = f2bf(acc[m][n][2] + bv);
        pk.w = f2bf(acc[m][n][3] + bv);
        *reinterpret_cast<u16x4*>(&vt_buf[((size_t)(h * HDIM + d)) * T_SEQ + t]) = pk;
      } else {
        unsigned short* dst = (part == 0) ? q_buf : k_buf;
#pragma unroll
        for (int jj = 0; jj < 4; ++jj) {
          int t = t0w + m * 16 + hi * 4 + jj;
          dst[((size_t)h * T_SEQ + t) * HDIM + d] = f2bf(acc[m][n][jj] + bv);
        }
      }
    }
  }
}

// ---- out-proj GEMM (R7-proven, FROZEN): counted dbuf, BK=64 --------------
__global__ __launch_bounds__(256) void out_gemm(
    const unsigned short* __restrict__ A, const unsigned short* __restrict__ B,
    const float* __restrict__ bias, const float* __restrict__ x_res,
    float* __restrict__ out) {
  const int K = DMODEL;
  constexpr int BM = 128, BN = 64;
  constexpr int NT = DMODEL / 64;
  constexpr int SM = BM / 2, SN = BN / 2;
  constexpr int MR = SM / 16, NR = SN / 16;
  constexpr int AL = BM / 32, BL = BN / 32;
  __shared__ __align__(16) unsigned short As[2 * BM * 64];
  __shared__ __align__(16) unsigned short Bs[2 * BN * 64];

  int tid = threadIdx.x;
  int lane = tid & 63, wave = tid >> 6;
  int wr = wave >> 1, wc = wave & 1;
  int lo = lane & 15, hi = lane >> 4;
  int t0 = blockIdx.y * BM, e0 = blockIdx.x * BN;

  f32x4 acc[MR][NR];
#pragma unroll
  for (int m = 0; m < MR; ++m)
#pragma unroll
    for (int n = 0; n < NR; ++n) acc[m][n] = (f32x4){0.f, 0.f, 0.f, 0.f};

  int c8 = (tid & 7) ^ ((tid >> 3) & 7);
  int srow = tid >> 3;
  const unsigned short* AbaseG = A + (size_t)(t0 + srow) * K + c8 * 8;
  const unsigned short* BbaseG = B + (size_t)(e0 + srow) * K + c8 * 8;
  unsigned short* ldsAu = As + wave * 512;
  unsigned short* ldsBu = Bs + wave * 512;

  auto stage = [&](int tt) {
    int k0 = tt * 64;
    int ab = (tt & 1) * (BM * 64);
    int bb = (tt & 1) * (BN * 64);
#pragma unroll
    for (int l = 0; l < AL; ++l)
      gload_lds16(AbaseG + (size_t)l * 32 * K + k0, ldsAu + l * 2048 + ab);
#pragma unroll
    for (int l = 0; l < BL; ++l)
      gload_lds16(BbaseG + (size_t)l * 32 * K + k0, ldsBu + l * 2048 + bb);
  };

  stage(0);
  asm volatile("s_waitcnt vmcnt(0) lgkmcnt(0)\n\ts_barrier" ::: "memory");

  for (int t = 0; t < NT; ++t) {
    if (t + 1 < NT) stage(t + 1);
    const unsigned short* Ab = As + (t & 1) * (BM * 64);
    const unsigned short* Bb = Bs + (t & 1) * (BN * 64);
    bf16x8 af[MR][2], bfr[NR][2];
#pragma unroll
    for (int m = 0; m < MR; ++m) {
      int row = wr * SM + m * 16 + lo;
#pragma unroll
      for (int ks = 0; ks < 2; ++ks)
        af[m][ks] = *reinterpret_cast<const bf16x8*>(
            &Ab[row * 64 + (((ks << 2) + hi) ^ (row & 7)) * 8]);
    }
#pragma unroll
    for (int n = 0; n < NR; ++n) {
      int row = wc * SN + n * 16 + lo;
#pragma unroll
      for (int ks = 0; ks < 2; ++ks)
        bfr[n][ks] = *reinterpret_cast<const bf16x8*>(
            &Bb[row * 64 + (((ks << 2) + hi) ^ (row & 7)) * 8]);
    }
#pragma unroll
    for (int ks = 0; ks < 2; ++ks)
#pragma unroll
      for (int m = 0; m < MR; ++m)
#pragma unroll
        for (int n = 0; n < NR; ++n)
          acc[m][n] = __builtin_amdgcn_mfma_f32_16x16x32_bf16(af[m][ks], bfr[n][ks],
                                                              acc[m][n], 0, 0, 0);
    asm volatile("s_waitcnt vmcnt(0) lgkmcnt(0)\n\ts_barrier" ::: "memory");
  }

  int t0w = t0 + wr * SM;
  int e0w = e0 + wc * SN;
#pragma unroll
  for (int m = 0; m < MR; ++m) {
#pragma unroll
    for (int n = 0; n < NR; ++n) {
      int e = e0w + n * 16 + lo;
      float bv = bias[e];
#pragma unroll
      for (int jj = 0; jj < 4; ++jj) {
        int t = t0w + m * 16 + hi * 4 + jj;
        size_t idxo = (size_t)t * DMODEL + e;
        out[idxo] = acc[m][n][jj] + bv + x_res[idxo];
      }
    }
  }
}

// ---------------- windowed flash attention (R14-frozen: QBLK=64) ----------
__global__ __launch_bounds__(256, 1) void win_attn(
    const unsigned short* __restrict__ q_buf,
    const unsigned short* __restrict__ k_buf,
    const unsigned short* __restrict__ vt_buf,
    unsigned short* __restrict__ ctx) {
  __shared__ __align__(16) unsigned short p_lds[4][4][16 * 40];
  int tid = threadIdx.x;
  int wave = tid >> 6;
  int lane = tid & 63;
  int lo = lane & 15, hi = lane >> 4;

  int id = blockIdx.x;
  int sw = (id & 7) * 32 + (id >> 3);
  int job = sw * 4 + wave;
  int h = job >> 6;
  int q0 = (job & 63) * 64;
  const float SC = 0.18033688011112042f;  // (1/sqrt(64)) * log2(e)

  bf16x8 aq[4][2];
#pragma unroll
  for (int u = 0; u < 4; ++u) {
    const unsigned short* qrow =
        q_buf + ((size_t)h * T_SEQ + q0 + u * 16 + lo) * HDIM + hi * 8;
    aq[u][0] = *reinterpret_cast<const bf16x8*>(qrow);
    aq[u][1] = *reinterpret_cast<const bf16x8*>(qrow + 32);
  }

  float L[4][4];
  f32x4 o[4][4];
#pragma unroll
  for (int u = 0; u < 4; ++u)
#pragma unroll
    for (int n = 0; n < 4; ++n) {
      o[u][n] = (f32x4){0.f, 0.f, 0.f, 0.f};
      L[u][n] = 0.f;
    }

  int jstart = q0 - WIN; if (jstart < 0) jstart = 0;
  int jend = q0 + 64 + WIN; if (jend > T_SEQ) jend = T_SEQ;

  for (int j0 = jstart; j0 < jend; j0 += 32) {
    bf16x8 kc[2][2];
#pragma unroll
    for (int c = 0; c < 2; ++c) {
      int krow = j0 + c * 16 + lo;
      if (krow > T_SEQ - 1) krow = T_SEQ - 1;
      const unsigned short* kp = k_buf + ((size_t)h * T_SEQ + krow) * HDIM + hi * 8;
      kc[c][0] = *reinterpret_cast<const bf16x8*>(kp);
      kc[c][1] = *reinterpret_cast<const bf16x8*>(kp + 32);
    }
    bf16x8 vc[4];
#pragma unroll
    for (int n = 0; n < 4; ++n)
      vc[n] = *reinterpret_cast<const bf16x8*>(
          vt_buf + ((size_t)(h * HDIM + n * 16 + lo)) * T_SEQ + j0 + hi * 8);
#pragma unroll
    for (int u = 0; u < 4; ++u) {
      f32x4 z[2];
      __builtin_amdgcn_s_setprio(1);
#pragma unroll
      for (int c = 0; c < 2; ++c) {
        z[c] = (f32x4){0.f, 0.f, 0.f, 0.f};
        z[c] = __builtin_amdgcn_mfma_f32_16x16x32_bf16(aq[u][0], kc[c][0], z[c], 0, 0, 0);
        z[c] = __builtin_amdgcn_mfma_f32_16x16x32_bf16(aq[u][1], kc[c][1], z[c], 0, 0, 0);
      }
      __builtin_amdgcn_s_setprio(0);
#pragma unroll
      for (int c = 0; c < 2; ++c) {
        int kj = j0 + c * 16 + lo;
#pragma unroll
        for (int jq = 0; jq < 4; ++jq) {
          int q = q0 + u * 16 + hi * 4 + jq;
          bool ok = (q - kj <= WIN) && (kj - q <= WIN);
          float p = ok ? __builtin_amdgcn_exp2f(z[c][jq] * SC) : 0.f;
          L[u][jq] += p;
          p_lds[wave][u][(hi * 4 + jq) * 40 + c * 16 + lo] = f2bf(p);
        }
      }
    }
    bf16x8 pa[4];
#pragma unroll
    for (int u = 0; u < 4; ++u)
      pa[u] = *reinterpret_cast<const bf16x8*>(&p_lds[wave][u][lo * 40 + hi * 8]);
    __builtin_amdgcn_s_setprio(1);
#pragma unroll
    for (int n = 0; n < 4; ++n)
#pragma unroll
      for (int u = 0; u < 4; ++u)
        o[u][n] = __builtin_amdgcn_mfma_f32_16x16x32_bf16(pa[u], vc[n], o[u][n], 0, 0, 0);
    __builtin_amdgcn_s_setprio(0);
  }
#pragma unroll
  for (int u = 0; u < 4; ++u)
#pragma unroll
    for (int jq = 0; jq < 4; ++jq) {
#pragma unroll
      for (int w = 1; w < 16; w <<= 1) L[u][jq] += __shfl_xor(L[u][jq], w, 64);
    }
#pragma unroll
  for (int u = 0; u < 4; ++u)
#pragma unroll
    for (int jq = 0; jq < 4; ++jq) {
      int t = q0 + u * 16 + hi * 4 + jq;
      float inv = 1.f / L[u][jq];
#pragma unroll
      for (int n = 0; n < 4; ++n)
        ctx[(size_t)t * DMODEL + h * HDIM + n * 16 + lo] = f2bf(o[u][n][jq] * inv);
    }
}

extern "C" void kernel_launch(void* const* d_in, const int* in_sizes, int n_in,
                              void* d_out, int out_size, void* d_ws, size_t ws_size,
                              hipStream_t stream) {
  const float* x = (const float*)d_in[0];
  const float* w_in = (const float*)d_in[1];
  const float* b_in = (const float*)d_in[2];
  const float* w_out = (const float*)d_in[3];
  const float* b_out = (const float*)d_in[4];
  float* out = (float*)d_out;

  char* ws = (char*)d_ws;
  size_t off = 0;
  auto take = [&](size_t bytes) {
    char* p = ws + off;
    off += (bytes + 255) & ~(size_t)255;
    return p;
  };
  unsigned short* x_bf = (unsigned short*)take((size_t)T_SEQ * DMODEL * 2);
  unsigned short* w_in_bf = (unsigned short*)take((size_t)3 * DMODEL * DMODEL * 2);
  unsigned short* w_out_bf = (unsigned short*)take((size_t)DMODEL * DMODEL * 2);
  unsigned short* q_buf = (unsigned short*)take((size_t)T_SEQ * DMODEL * 2);
  unsigned short* k_buf = (unsigned short*)take((size_t)T_SEQ * DMODEL * 2);
  unsigned short* vt_buf = (unsigned short*)take((size_t)T_SEQ * DMODEL * 2 + 8192);
  unsigned short* ctx = (unsigned short*)take((size_t)T_SEQ * DMODEL * 2);

  convert_all<<<2048, 256, 0, stream>>>(x, w_in, w_out, x_bf, w_in_bf, w_out_bf);

  // qkv: M=4096, N=3072, tile 256x256 -> grid (12, 16) = 192 blocks, 512 thr
  dim3 g1(3 * DMODEL / 256, T_SEQ / 256);
  qkv_gemm8<<<g1, 512, 0, stream>>>(x_bf, w_in_bf, b_in, q_buf, k_buf, vt_buf);

  win_attn<<<256, 256, 0, stream>>>(q_buf, k_buf, vt_buf, ctx);

  // out-proj: M=4096, N=1024, tile 128x64 -> grid (16, 32) = 512 blocks
  dim3 g2(DMODEL / 64, T_SEQ / 128);
  out_gemm<<<g2, 256, 0, stream>>>(ctx, w_out_bf, b_out, x, out);
}

// Round 16
// 87.999 us; speedup vs baseline: 1.1370x; 1.1370x over previous
//
#include <hip/hip_runtime.h>

#define T_SEQ 4096
#define DMODEL 1024
#define NHEAD 16
#define HDIM 64
#define WIN 128

typedef __attribute__((ext_vector_type(8))) short bf16x8;
typedef __attribute__((ext_vector_type(4))) float f32x4;
typedef __attribute__((ext_vector_type(4))) unsigned short u16x4;

__device__ __forceinline__ unsigned short f2bf(float f) {
  unsigned int u = __builtin_bit_cast(unsigned int, f);
  return (unsigned short)((u + 0x7fffu + ((u >> 16) & 1u)) >> 16);
}

__device__ __forceinline__ void gload_lds16(const unsigned short* g,
                                            unsigned short* l) {
  __builtin_amdgcn_global_load_lds(
      (const __attribute__((address_space(1))) void*)g,
      (__attribute__((address_space(3))) void*)l, 16, 0, 0);
}

// ---------------- fused fp32 -> bf16 converts (one launch) ----------------
__global__ void convert_all(const float* __restrict__ x,
                            const float* __restrict__ w_in,
                            const float* __restrict__ w_out,
                            unsigned short* __restrict__ x_bf,
                            unsigned short* __restrict__ w_in_bf,
                            unsigned short* __restrict__ w_out_bf) {
  int stride = gridDim.x * blockDim.x;
  int t0 = blockIdx.x * blockDim.x + threadIdx.x;
#define CVT(SRC, DST, N4)                                          \
  for (int i = t0; i < (N4); i += stride) {                        \
    float4 v = reinterpret_cast<const float4*>(SRC)[i];            \
    u16x4 o;                                                       \
    o.x = f2bf(v.x); o.y = f2bf(v.y); o.z = f2bf(v.z); o.w = f2bf(v.w); \
    reinterpret_cast<u16x4*>(DST)[i] = o;                          \
  }
  CVT(x, x_bf, T_SEQ * DMODEL / 4)
  CVT(w_in, w_in_bf, 3 * DMODEL * DMODEL / 4)
  CVT(w_out, w_out_bf, DMODEL * DMODEL / 4)
#undef CVT
}

// ---- GEMM body (R7-proven, FROZEN): counted double-buffer, BK=64 ---------
// STAGE(t+1) before compute(t); one raw {vmcnt(0),lgkmcnt(0),s_barrier} per
// K-tile. LDS linear; global source pre-XOR-swizzled; reads XOR back
// (0 bank conflicts). EPI 0: qkv epilogue; EPI 1: out epilogue.
// Pipeline-variant ledger (do not revisit): R8 XCD-ownership +-0,
// R9 3-buf counted -10us, R12 4-slot counted -5us, R15 8-phase -11us.
template <int EPI, int BM, int BN>
__device__ __forceinline__ void gemm_body(
    const unsigned short* __restrict__ A,
    const unsigned short* __restrict__ B,
    const float* __restrict__ bias,
    unsigned short* __restrict__ q_buf,
    unsigned short* __restrict__ k_buf,
    unsigned short* __restrict__ vt_buf,
    const float* __restrict__ x_res,
    float* __restrict__ out) {
  const int K = DMODEL;
  constexpr int NT = DMODEL / 64;           // 16 K-tiles
  constexpr int SM = BM / 2, SN = BN / 2;   // per-wave spans
  constexpr int MR = SM / 16, NR = SN / 16;
  constexpr int AL = BM / 32, BL = BN / 32; // 16B stage loads per thread
  __shared__ __align__(16) unsigned short As[2 * BM * 64];
  __shared__ __align__(16) unsigned short Bs[2 * BN * 64];

  int tid = threadIdx.x;
  int lane = tid & 63, wave = tid >> 6;
  int wr = wave >> 1, wc = wave & 1;
  int lo = lane & 15, hi = lane >> 4;
  int t0 = blockIdx.y * BM, e0 = blockIdx.x * BN;

  f32x4 acc[MR][NR];
#pragma unroll
  for (int m = 0; m < MR; ++m)
#pragma unroll
    for (int n = 0; n < NR; ++n) acc[m][n] = (f32x4){0.f, 0.f, 0.f, 0.f};

  int c8 = (tid & 7) ^ ((tid >> 3) & 7);
  int srow = tid >> 3;  // + l*32 per load
  const unsigned short* AbaseG = A + (size_t)(t0 + srow) * K + c8 * 8;
  const unsigned short* BbaseG = B + (size_t)(e0 + srow) * K + c8 * 8;
  unsigned short* ldsAu = As + wave * 512;
  unsigned short* ldsBu = Bs + wave * 512;

  auto stage = [&](int tt) {
    int k0 = tt * 64;
    int ab = (tt & 1) * (BM * 64);
    int bb = (tt & 1) * (BN * 64);
#pragma unroll
    for (int l = 0; l < AL; ++l)
      gload_lds16(AbaseG + (size_t)l * 32 * K + k0, ldsAu + l * 2048 + ab);
#pragma unroll
    for (int l = 0; l < BL; ++l)
      gload_lds16(BbaseG + (size_t)l * 32 * K + k0, ldsBu + l * 2048 + bb);
  };

  stage(0);
  asm volatile("s_waitcnt vmcnt(0) lgkmcnt(0)\n\ts_barrier" ::: "memory");

  for (int t = 0; t < NT; ++t) {
    if (t + 1 < NT) stage(t + 1);
    const unsigned short* Ab = As + (t & 1) * (BM * 64);
    const unsigned short* Bb = Bs + (t & 1) * (BN * 64);
    bf16x8 af[MR][2], bfr[NR][2];
#pragma unroll
    for (int m = 0; m < MR; ++m) {
      int row = wr * SM + m * 16 + lo;
#pragma unroll
      for (int ks = 0; ks < 2; ++ks)
        af[m][ks] = *reinterpret_cast<const bf16x8*>(
            &Ab[row * 64 + (((ks << 2) + hi) ^ (row & 7)) * 8]);
    }
#pragma unroll
    for (int n = 0; n < NR; ++n) {
      int row = wc * SN + n * 16 + lo;
#pragma unroll
      for (int ks = 0; ks < 2; ++ks)
        bfr[n][ks] = *reinterpret_cast<const bf16x8*>(
            &Bb[row * 64 + (((ks << 2) + hi) ^ (row & 7)) * 8]);
    }
#pragma unroll
    for (int ks = 0; ks < 2; ++ks)
#pragma unroll
      for (int m = 0; m < MR; ++m)
#pragma unroll
        for (int n = 0; n < NR; ++n)
          acc[m][n] = __builtin_amdgcn_mfma_f32_16x16x32_bf16(af[m][ks], bfr[n][ks],
                                                              acc[m][n], 0, 0, 0);
    asm volatile("s_waitcnt vmcnt(0) lgkmcnt(0)\n\ts_barrier" ::: "memory");
  }

  int t0w = t0 + wr * SM;
  int e0w = e0 + wc * SN;
#pragma unroll
  for (int m = 0; m < MR; ++m) {
#pragma unroll
    for (int n = 0; n < NR; ++n) {
      int e = e0w + n * 16 + lo;
      float bv = bias[e];
      if (EPI == 0) {
        int part = e >> 10;
        int h = (e >> 6) & 15;
        int d = e & 63;
        if (part == 2) {
          int t = t0w + m * 16 + hi * 4;
          u16x4 pk;
          pk.x = f2bf(acc[m][n][0] + bv);
          pk.y = f2bf(acc[m][n][1] + bv);
          pk.z = f2bf(acc[m][n][2] + bv);
          pk.w = f2bf(acc[m][n][3] + bv);
          *reinterpret_cast<u16x4*>(&vt_buf[((size_t)(h * HDIM + d)) * T_SEQ + t]) = pk;
        } else {
          unsigned short* dst = (part == 0) ? q_buf : k_buf;
#pragma unroll
          for (int jj = 0; jj < 4; ++jj) {
            int t = t0w + m * 16 + hi * 4 + jj;
            dst[((size_t)h * T_SEQ + t) * HDIM + d] = f2bf(acc[m][n][jj] + bv);
          }
        }
      } else {
#pragma unroll
        for (int jj = 0; jj < 4; ++jj) {
          int t = t0w + m * 16 + hi * 4 + jj;
          size_t idxo = (size_t)t * DMODEL + e;
          out[idxo] = acc[m][n][jj] + bv + x_res[idxo];
        }
      }
    }
  }
}

__global__ __launch_bounds__(256) void qkv_gemm(
    const unsigned short* __restrict__ A, const unsigned short* __restrict__ B,
    const float* __restrict__ bias, unsigned short* __restrict__ q_buf,
    unsigned short* __restrict__ k_buf, unsigned short* __restrict__ vt_buf) {
  gemm_body<0, 128, 192>(A, B, bias, q_buf, k_buf, vt_buf, nullptr, nullptr);
}

__global__ __launch_bounds__(256) void out_gemm(
    const unsigned short* __restrict__ A, const unsigned short* __restrict__ B,
    const float* __restrict__ bias, const float* __restrict__ x_res,
    float* __restrict__ out) {
  gemm_body<1, 128, 64>(A, B, bias, nullptr, nullptr, nullptr, x_res, out);
}

// ---------------- windowed flash attention (R14-best: QBLK=64, KBLK=32) ---
// 1 wave per (head, 64-query tile): window = 320 keys = 10 k-tiles per 64
// queries. No-max softmax (scores bounded -> exp2 direct, single end
// reduction). Per-wave LDS P slices, no barriers; setprio around MFMA (T5).
// Attn-variant ledger: k-split -5us, V-prefetch +-0, KBLK=64 -2us,
// QBLK 16->32->64 = -13us, -1.5us.
__global__ __launch_bounds__(256, 1) void win_attn(
    const unsigned short* __restrict__ q_buf,
    const unsigned short* __restrict__ k_buf,
    const unsigned short* __restrict__ vt_buf,
    unsigned short* __restrict__ ctx) {
  __shared__ __align__(16) unsigned short p_lds[4][4][16 * 40];
  int tid = threadIdx.x;
  int wave = tid >> 6;
  int lane = tid & 63;
  int lo = lane & 15, hi = lane >> 4;

  int id = blockIdx.x;
  int sw = (id & 7) * 32 + (id >> 3);  // 256 blocks, bijective XCD swizzle
  int job = sw * 4 + wave;             // 1024 jobs
  int h = job >> 6;                    // 64 q-tiles (of 64) per head
  int q0 = (job & 63) * 64;
  const float SC = 0.18033688011112042f;  // (1/sqrt(64)) * log2(e)

  bf16x8 aq[4][2];
#pragma unroll
  for (int u = 0; u < 4; ++u) {
    const unsigned short* qrow =
        q_buf + ((size_t)h * T_SEQ + q0 + u * 16 + lo) * HDIM + hi * 8;
    aq[u][0] = *reinterpret_cast<const bf16x8*>(qrow);
    aq[u][1] = *reinterpret_cast<const bf16x8*>(qrow + 32);
  }

  float L[4][4];
  f32x4 o[4][4];
#pragma unroll
  for (int u = 0; u < 4; ++u)
#pragma unroll
    for (int n = 0; n < 4; ++n) {
      o[u][n] = (f32x4){0.f, 0.f, 0.f, 0.f};
      L[u][n] = 0.f;
    }

  int jstart = q0 - WIN; if (jstart < 0) jstart = 0;
  int jend = q0 + 64 + WIN; if (jend > T_SEQ) jend = T_SEQ;

  for (int j0 = jstart; j0 < jend; j0 += 32) {
    bf16x8 kc[2][2];
#pragma unroll
    for (int c = 0; c < 2; ++c) {
      int krow = j0 + c * 16 + lo;
      if (krow > T_SEQ - 1) krow = T_SEQ - 1;  // clamp; masked below
      const unsigned short* kp = k_buf + ((size_t)h * T_SEQ + krow) * HDIM + hi * 8;
      kc[c][0] = *reinterpret_cast<const bf16x8*>(kp);
      kc[c][1] = *reinterpret_cast<const bf16x8*>(kp + 32);
    }
    bf16x8 vc[4];
#pragma unroll
    for (int n = 0; n < 4; ++n)
      vc[n] = *reinterpret_cast<const bf16x8*>(
          vt_buf + ((size_t)(h * HDIM + n * 16 + lo)) * T_SEQ + j0 + hi * 8);
#pragma unroll
    for (int u = 0; u < 4; ++u) {
      f32x4 z[2];
      __builtin_amdgcn_s_setprio(1);
#pragma unroll
      for (int c = 0; c < 2; ++c) {
        z[c] = (f32x4){0.f, 0.f, 0.f, 0.f};
        z[c] = __builtin_amdgcn_mfma_f32_16x16x32_bf16(aq[u][0], kc[c][0], z[c], 0, 0, 0);
        z[c] = __builtin_amdgcn_mfma_f32_16x16x32_bf16(aq[u][1], kc[c][1], z[c], 0, 0, 0);
      }
      __builtin_amdgcn_s_setprio(0);
#pragma unroll
      for (int c = 0; c < 2; ++c) {
        int kj = j0 + c * 16 + lo;
#pragma unroll
        for (int jq = 0; jq < 4; ++jq) {
          int q = q0 + u * 16 + hi * 4 + jq;
          bool ok = (q - kj <= WIN) && (kj - q <= WIN);
          float p = ok ? __builtin_amdgcn_exp2f(z[c][jq] * SC) : 0.f;
          L[u][jq] += p;
          p_lds[wave][u][(hi * 4 + jq) * 40 + c * 16 + lo] = f2bf(p);
        }
      }
    }
    bf16x8 pa[4];
#pragma unroll
    for (int u = 0; u < 4; ++u)
      pa[u] = *reinterpret_cast<const bf16x8*>(&p_lds[wave][u][lo * 40 + hi * 8]);
    __builtin_amdgcn_s_setprio(1);
#pragma unroll
    for (int n = 0; n < 4; ++n)
#pragma unroll
      for (int u = 0; u < 4; ++u)
        o[u][n] = __builtin_amdgcn_mfma_f32_16x16x32_bf16(pa[u], vc[n], o[u][n], 0, 0, 0);
    __builtin_amdgcn_s_setprio(0);
  }
#pragma unroll
  for (int u = 0; u < 4; ++u)
#pragma unroll
    for (int jq = 0; jq < 4; ++jq) {
#pragma unroll
      for (int w = 1; w < 16; w <<= 1) L[u][jq] += __shfl_xor(L[u][jq], w, 64);
    }
#pragma unroll
  for (int u = 0; u < 4; ++u)
#pragma unroll
    for (int jq = 0; jq < 4; ++jq) {
      int t = q0 + u * 16 + hi * 4 + jq;
      float inv = 1.f / L[u][jq];
#pragma unroll
      for (int n = 0; n < 4; ++n)
        ctx[(size_t)t * DMODEL + h * HDIM + n * 16 + lo] = f2bf(o[u][n][jq] * inv);
    }
}

extern "C" void kernel_launch(void* const* d_in, const int* in_sizes, int n_in,
                              void* d_out, int out_size, void* d_ws, size_t ws_size,
                              hipStream_t stream) {
  const float* x = (const float*)d_in[0];
  const float* w_in = (const float*)d_in[1];
  const float* b_in = (const float*)d_in[2];
  const float* w_out = (const float*)d_in[3];
  const float* b_out = (const float*)d_in[4];
  float* out = (float*)d_out;

  char* ws = (char*)d_ws;
  size_t off = 0;
  auto take = [&](size_t bytes) {
    char* p = ws + off;
    off += (bytes + 255) & ~(size_t)255;
    return p;
  };
  unsigned short* x_bf = (unsigned short*)take((size_t)T_SEQ * DMODEL * 2);
  unsigned short* w_in_bf = (unsigned short*)take((size_t)3 * DMODEL * DMODEL * 2);
  unsigned short* w_out_bf = (unsigned short*)take((size_t)DMODEL * DMODEL * 2);
  unsigned short* q_buf = (unsigned short*)take((size_t)T_SEQ * DMODEL * 2);
  unsigned short* k_buf = (unsigned short*)take((size_t)T_SEQ * DMODEL * 2);
  unsigned short* vt_buf = (unsigned short*)take((size_t)T_SEQ * DMODEL * 2 + 8192);
  unsigned short* ctx = (unsigned short*)take((size_t)T_SEQ * DMODEL * 2);

  convert_all<<<2048, 256, 0, stream>>>(x, w_in, w_out, x_bf, w_in_bf, w_out_bf);

  // qkv: M=4096, N=3072, tile 128x192 -> grid (16, 32) = 512 blocks
  dim3 g1(3 * DMODEL / 192, T_SEQ / 128);
  qkv_gemm<<<g1, 256, 0, stream>>>(x_bf, w_in_bf, b_in, q_buf, k_buf, vt_buf);

  win_attn<<<256, 256, 0, stream>>>(q_buf, k_buf, vt_buf, ctx);

  // out-proj: M=4096, N=1024, tile 128x64 -> grid (16, 32) = 512 blocks
  dim3 g2(DMODEL / 64, T_SEQ / 128);
  out_gemm<<<g2, 256, 0, stream>>>(ctx, w_out_bf, b_out, x, out);
}